// Round 2
// baseline (248.954 us; speedup 1.0000x reference)
//
#include <hip/hip_runtime.h>
#include <hip/hip_bf16.h>

#define BB 16
#define NN 1024
#define DIN 64
#define KK 8
#define DP 64

typedef __bf16 bf16x8 __attribute__((ext_vector_type(8)));
typedef float f32x16 __attribute__((ext_vector_type(16)));

// ws layout: z bf16 [K][B*N][DP]  = 8*16384*64*2 B = 16 MiB at offset 0
//            Wt bf16 [K][DP][DIN] = 64 KiB at offset 16 MiB
#define Z_BYTES (16777216UL)

// ---------------------------------------------------------------------------
// Kernel 0: Wt[k][e][d] = bf16(W[k][d][e])   (8 blocks, one per k)
// ---------------------------------------------------------------------------
__global__ __launch_bounds__(256) void wt_kernel(const float* __restrict__ W,
                                                 __hip_bfloat16* __restrict__ Wt)
{
    __shared__ float Wl[DIN * DP];
    const int k = blockIdx.x;
    const int tid = threadIdx.x;

    const float4* src = (const float4*)(W + (size_t)k * DIN * DP);
    float4* dst = (float4*)Wl;
    #pragma unroll
    for (int i = 0; i < 4; ++i) dst[tid + i * 256] = src[tid + i * 256];
    __syncthreads();

    const int e  = tid >> 2;          // 0..63
    const int dc = (tid & 3) * 16;    // d-chunk
    __hip_bfloat16 v[16];
    #pragma unroll
    for (int i = 0; i < 16; ++i)
        v[i] = __float2bfloat16(Wl[(dc + i) * DP + e]);
    // 16 bf16 = 32 B contiguous at Wt[k][e][dc]
    *(uint4*)(Wt + ((size_t)k * DP + e) * DIN + dc)     = *(uint4*)&v[0];
    *(uint4*)(Wt + ((size_t)k * DP + e) * DIN + dc + 8) = *(uint4*)&v[8];
}

// ---------------------------------------------------------------------------
// Kernel 1: z[k][row][e] = relu(sum_d x[row][d] * W[k][d][e] + bias[k][e]), bf16
// MFMA: D = mfma(A = Wt rows (i=e), B = x rows (j=row)) -> D[e][row] = z[row][e].
// Any K-slot permutation cancels (both operands loaded with identical chunking).
// C/D layout (HW-verified): col = lane&31 (row), row_i = (r&3)+8*(r>>2)+4*h (e).
// Grid = 512 blocks (32 x-rows each), 4 waves: wave w -> attrs 2w, 2w+1.
// ---------------------------------------------------------------------------
__global__ __launch_bounds__(256) void enc_kernel(const float* __restrict__ x,
                                                  const __hip_bfloat16* __restrict__ Wt,
                                                  const float* __restrict__ bias,
                                                  __hip_bfloat16* __restrict__ z)
{
    const int tid  = threadIdx.x;
    const int lane = tid & 63;
    const int wid  = tid >> 6;
    const int l31  = lane & 31;
    const int h    = lane >> 5;
    const int row0 = blockIdx.x * 32;
    const int row  = row0 + l31;      // this lane's x-row (B-operand col)

    // B-frags: x rows, fp32 -> bf16, 4 K-chunks of 16 (this lane: h*8..h*8+7)
    bf16x8 xb[4];
    #pragma unroll
    for (int kk = 0; kk < 4; ++kk) {
        const float* xp = x + (size_t)row * DIN + kk * 16 + h * 8;
        float4 lo = *(const float4*)xp;
        float4 hi = *(const float4*)(xp + 4);
        bf16x8 t;
        t[0] = (__bf16)lo.x; t[1] = (__bf16)lo.y; t[2] = (__bf16)lo.z; t[3] = (__bf16)lo.w;
        t[4] = (__bf16)hi.x; t[5] = (__bf16)hi.y; t[6] = (__bf16)hi.z; t[7] = (__bf16)hi.w;
        xb[kk] = t;
    }

    #pragma unroll
    for (int a = 0; a < 2; ++a) {
        const int k = wid * 2 + a;
        #pragma unroll
        for (int et = 0; et < 2; ++et) {
            f32x16 acc;
            #pragma unroll
            for (int i = 0; i < 16; ++i) acc[i] = 0.0f;
            const __hip_bfloat16* wp =
                Wt + ((size_t)k * DP + et * 32 + l31) * DIN + h * 8;
            #pragma unroll
            for (int kk = 0; kk < 4; ++kk) {
                bf16x8 wf = *(const bf16x8*)(wp + kk * 16);
                acc = __builtin_amdgcn_mfma_f32_32x32x16_bf16(wf, xb[kk], acc, 0, 0, 0);
            }
            // lane holds 16 e-values for fixed row; groups of 4 regs are
            // 4 consecutive e at e0 = et*32 + 8*g + 4*h
            #pragma unroll
            for (int g = 0; g < 4; ++g) {
                const int e0 = et * 32 + 8 * g + 4 * h;
                float4 b4 = *(const float4*)(bias + k * DP + e0);
                union { __hip_bfloat16 b[4]; uint2 u; } pk;
                pk.b[0] = __float2bfloat16(fmaxf(acc[g * 4 + 0] + b4.x, 0.0f));
                pk.b[1] = __float2bfloat16(fmaxf(acc[g * 4 + 1] + b4.y, 0.0f));
                pk.b[2] = __float2bfloat16(fmaxf(acc[g * 4 + 2] + b4.z, 0.0f));
                pk.b[3] = __float2bfloat16(fmaxf(acc[g * 4 + 3] + b4.w, 0.0f));
                *(uint2*)(z + ((size_t)k * BB * NN + row) * DP + e0) = pk.u;
            }
        }
    }
}

// ---------------------------------------------------------------------------
// Kernel 2: R[b][n][m][k] = sum_e z[k][b][n][e] * z[k][b][m][e]
// One wave = 32n x 32m x ALL 8 k (8 f32x16 accs). Lane (l31,h) then owns all
// 8 k for (n_r, m=m0+l31) -> direct coalesced dwordx4 x2 stores, no LDS.
// Block = 4 waves in 2x2 (64x64 tile). Grid = 16 * 16 * 16.
// Gram symmetry: A/B frags loaded identically -> K-slot permutation cancels.
// ---------------------------------------------------------------------------
__global__ __launch_bounds__(256, 2) void gram_kernel(const __hip_bfloat16* __restrict__ z,
                                                      float* __restrict__ out)
{
    const int bid = blockIdx.x;
    const int mt2 = bid & 15;
    const int nt2 = (bid >> 4) & 15;
    const int b   = bid >> 8;
    const int tid  = threadIdx.x;
    const int lane = tid & 63;
    const int wid  = tid >> 6;
    const int l31  = lane & 31;
    const int h    = lane >> 5;

    const int n0 = nt2 * 64 + (wid >> 1) * 32;
    const int m0 = mt2 * 64 + (wid & 1) * 32;

    // flat z row = k*B*N + b*N + n ; element = row*DP + e
    const size_t rowA = (size_t)b * NN + n0 + l31;
    const size_t rowB = (size_t)b * NN + m0 + l31;
    const size_t kstride = (size_t)BB * NN * DP;   // elems per attribute slice

    f32x16 acc[8];
    #pragma unroll
    for (int k = 0; k < 8; ++k)
        #pragma unroll
        for (int i = 0; i < 16; ++i) acc[k][i] = 0.0f;

    #pragma unroll
    for (int kk = 0; kk < 4; ++kk) {
        const size_t eo = (size_t)kk * 16 + h * 8;
        bf16x8 af[8], bf[8];
        #pragma unroll
        for (int k = 0; k < 8; ++k) {
            af[k] = *(const bf16x8*)(z + (size_t)k * kstride + rowA * DP + eo);
            bf[k] = *(const bf16x8*)(z + (size_t)k * kstride + rowB * DP + eo);
        }
        #pragma unroll
        for (int k = 0; k < 8; ++k)
            acc[k] = __builtin_amdgcn_mfma_f32_32x32x16_bf16(af[k], bf[k], acc[k], 0, 0, 0);
    }

    // store: lane owns (n_r, m0+l31), all 8 k contiguous in output
    float* ob = out + (((size_t)b * NN) * NN) * KK;
    #pragma unroll
    for (int r = 0; r < 16; ++r) {
        const int n = n0 + (r & 3) + 8 * (r >> 2) + 4 * h;
        float* p = ob + ((size_t)n * NN + m0 + l31) * KK;
        float4 v0 = make_float4(acc[0][r], acc[1][r], acc[2][r], acc[3][r]);
        float4 v1 = make_float4(acc[4][r], acc[5][r], acc[6][r], acc[7][r]);
        *(float4*)p       = v0;
        *(float4*)(p + 4) = v1;
    }
}

// ---------------------------------------------------------------------------
extern "C" void kernel_launch(void* const* d_in, const int* in_sizes, int n_in,
                              void* d_out, int out_size, void* d_ws, size_t ws_size,
                              hipStream_t stream)
{
    const float* x    = (const float*)d_in[0];
    const float* W    = (const float*)d_in[1];
    const float* bias = (const float*)d_in[2];
    float* out        = (float*)d_out;
    __hip_bfloat16* z  = (__hip_bfloat16*)d_ws;
    __hip_bfloat16* Wt = (__hip_bfloat16*)((char*)d_ws + Z_BYTES);

    wt_kernel <<<dim3(KK),            dim3(256), 0, stream>>>(W, Wt);
    enc_kernel<<<dim3(BB * NN / 32),  dim3(256), 0, stream>>>(x, Wt, bias, z);
    gram_kernel<<<dim3(BB * 16 * 16), dim3(256), 0, stream>>>(z, out);
}